// Round 8
// baseline (118.141 us; speedup 1.0000x reference)
//
#include <hip/hip_runtime.h>
#include <hip/hip_bf16.h>
#include <stdint.h>

#define DM 1024
#define NH 16
#define DKq 64
#define SS 2048

// fold 1/sqrt(Dk)=1/8 and log2(e) into K so P = exp2(S) directly
#define SCALE_K 0.18033688011112042f

typedef __bf16 bf16x8 __attribute__((ext_vector_type(8)));
typedef __bf16 bf16x4 __attribute__((ext_vector_type(4)));
typedef float f32x4 __attribute__((ext_vector_type(4)));
typedef float f32x16 __attribute__((ext_vector_type(16)));
typedef unsigned short u16x8 __attribute__((ext_vector_type(8)));

static __device__ __forceinline__ unsigned short f2bf(float f) {
  union { float f; unsigned u; } v; v.f = f;
  unsigned r = v.u + 0x7FFFu + ((v.u >> 16) & 1u);
  return (unsigned short)(r >> 16);
}

static __device__ __forceinline__ float fexp2(float x) {
  float r; asm("v_exp_f32 %0, %1" : "=v"(r) : "v"(x)); return r;
}

static __device__ __forceinline__ void gload_lds16(const void* g, void* l) {
  __builtin_amdgcn_global_load_lds((const __attribute__((address_space(1))) void*)g,
                                   (__attribute__((address_space(3))) void*)l, 16, 0, 0);
}

// ---- fused casts: X fp32->bf16, W{q,k,v} fp32->bf16 (Wk scaled) ----
__global__ void cast_all(const float* __restrict__ Q, const float* __restrict__ wq,
                         const float* __restrict__ wk, const float* __restrict__ wv,
                         unsigned short* __restrict__ Xb, unsigned short* __restrict__ W3) {
  int i = blockIdx.x * blockDim.x + threadIdx.x;  // 0 .. 917503
  const int nX8 = 4096 * 1024 / 8;                // 524288
  if (i < nX8) {
    const float4* s = reinterpret_cast<const float4*>(Q) + (size_t)i * 2;
    float4 a = s[0], b = s[1];
    u16x8 o;
    o[0]=f2bf(a.x); o[1]=f2bf(a.y); o[2]=f2bf(a.z); o[3]=f2bf(a.w);
    o[4]=f2bf(b.x); o[5]=f2bf(b.y); o[6]=f2bf(b.z); o[7]=f2bf(b.w);
    *reinterpret_cast<u16x8*>(Xb + (size_t)i * 8) = o;
  } else {
    int j = i - nX8;                 // 0 .. 393215
    int which = j >> 17;             // 131072 chunks per matrix
    int local = j & 131071;
    float sc = (which == 1) ? SCALE_K : 1.0f;
    const float* s = (which == 0 ? wq : (which == 1 ? wk : wv)) + (size_t)local * 8;
    float4 a = *(const float4*)s, b = *(const float4*)(s + 4);
    u16x8 o;
    o[0]=f2bf(a.x*sc); o[1]=f2bf(a.y*sc); o[2]=f2bf(a.z*sc); o[3]=f2bf(a.w*sc);
    o[4]=f2bf(b.x*sc); o[5]=f2bf(b.y*sc); o[6]=f2bf(b.z*sc); o[7]=f2bf(b.w*sc);
    *reinterpret_cast<u16x8*>(W3 + (size_t)j * 8) = o;
  }
}

// ---- fused QKV projection: [4096,1024] @ [3072,1024]^T + bias -> q/k (bhsd) , v (bhds) ----
__launch_bounds__(256)
__global__ void proj_gemm(const unsigned short* __restrict__ X, const unsigned short* __restrict__ W3,
                          const float* __restrict__ bq, const float* __restrict__ bk,
                          const float* __restrict__ bv,
                          unsigned short* __restrict__ qb, unsigned short* __restrict__ kbuf,
                          unsigned short* __restrict__ vt) {
  __shared__ __align__(16) unsigned short Ab[128 * 32];
  __shared__ __align__(16) unsigned short Bb[128 * 32];
  const int m0 = blockIdx.x * 128, n0 = blockIdx.y * 128;
  const int tid = threadIdx.x;
  const int w = tid >> 6, lane = tid & 63;
  const int i16 = lane & 15, kg = lane >> 4;
  const int wr = w >> 1, wc = w & 1;

  const int arow = tid >> 2, acol = (tid & 3) * 8;
  const unsigned short* Xp = X + (size_t)(m0 + arow) * DM + acol;
  const unsigned short* Wp = W3 + (size_t)(n0 + arow) * DM + acol;
  char* AbC = (char*)Ab;
  char* BbC = (char*)Bb;

  const f32x4 fz = {0.f, 0.f, 0.f, 0.f};
  f32x4 acc[4][4];
#pragma unroll
  for (int m = 0; m < 4; ++m)
#pragma unroll
    for (int n = 0; n < 4; ++n) acc[m][n] = fz;

  for (int k0 = 0; k0 < DM; k0 += 32) {
    gload_lds16(Xp + k0,            AbC + w * 1024);
    gload_lds16(Xp + 64 * DM + k0,  AbC + 4096 + w * 1024);
    gload_lds16(Wp + k0,            BbC + w * 1024);
    gload_lds16(Wp + 64 * DM + k0,  BbC + 4096 + w * 1024);
    __syncthreads();
    bf16x8 af[4], bfr[4];
#pragma unroll
    for (int m = 0; m < 4; ++m)
      af[m] = *(const bf16x8*)(AbC + ((wr * 64 + m * 16 + i16) * 32 + kg * 8) * 2);
#pragma unroll
    for (int n = 0; n < 4; ++n)
      bfr[n] = *(const bf16x8*)(BbC + ((wc * 64 + n * 16 + i16) * 32 + kg * 8) * 2);
#pragma unroll
    for (int m = 0; m < 4; ++m)
#pragma unroll
      for (int n = 0; n < 4; ++n)
        acc[m][n] = __builtin_amdgcn_mfma_f32_16x16x32_bf16(af[m], bfr[n], acc[m][n], 0, 0, 0);
    __syncthreads();
  }

#pragma unroll
  for (int n = 0; n < 4; ++n) {
    int ncol = n0 + wc * 64 + n * 16 + i16;
    int which = ncol >> 10, nn = ncol & 1023;
    const float* bias = (which == 0) ? bq : (which == 1) ? bk : bv;
    float bsv = bias[nn];
    if (which == 1) bsv *= SCALE_K;
    int h = nn >> 6, d = nn & 63;
#pragma unroll
    for (int m = 0; m < 4; ++m) {
      int rbase = m0 + wr * 64 + m * 16 + kg * 4;
#pragma unroll
      for (int e = 0; e < 4; ++e) {
        int r = rbase + e;
        int bI = r >> 11, s = r & 2047;
        if (which == 2) {
          vt[(((size_t)bI * NH + h) * DKq + d) * SS + s] = f2bf(acc[m][n][e] + bsv);
        } else {
          unsigned short* dst = (which == 0) ? qb : kbuf;
          dst[(((size_t)bI * NH + h) * SS + s) * DKq + d] = f2bf(acc[m][n][e] + bsv);
        }
      }
    }
  }
}

// ---- attention v6: proven sync skeleton + conflict-free chunk-permuted LDS
// layouts (contiguous per ds_read inst, no XOR) + per-block tile stagger +
// tree dsum. 2-wave blocks over 64 q rows, grid 1024. ----
__launch_bounds__(128)
__global__ void attn6(const unsigned short* __restrict__ qb, const unsigned short* __restrict__ kbuf,
                      const unsigned short* __restrict__ vt, float* __restrict__ out) {
  __shared__ __align__(16) unsigned short KV[2][8192];  // [buf][K:0..4095 | V:4096..8191] = 32 KB
  const int bid = blockIdx.x;
  const int work = (bid & 7) * 128 + (bid >> 3);  // XCD-grouped: 4 (b,h) per XCD
  const int qt = work & 31, h = (work >> 5) & 15, b = work >> 9;
  const int tid = threadIdx.x, w = tid >> 6, lane = tid & 63;
  const int l31 = lane & 31, hi = lane >> 5;

  const size_t bh = (size_t)b * NH + h;
  const unsigned short* qsrc = qb + (bh * SS + qt * 64 + w * 32) * DKq;
  const unsigned short* kbase = kbuf + bh * SS * DKq;
  const unsigned short* vbase = vt + bh * DKq * SS;

  // Q frags: B-operand of mfma(K,Q): lane holds Q[q = l31][kd = m*16 + hi*8 + j]
  bf16x8 Qf[4];
#pragma unroll
  for (int m = 0; m < 4; ++m)
    Qf[m] = *(const bf16x8*)(qsrc + (size_t)l31 * DKq + m * 16 + hi * 8);

  // Chunk-permuted staging (dest forced linear-in-lane; content chosen so reads
  // are contiguous per instruction):
  //  K chunk c = m*128 + hi*64 + kbk*32 + r  -> content K[kbk*32+r][(2m+hi)*8 ..+7]
  //  V chunk c = S*64  + dblk*32 + dl       -> content V^T[dblk*32+dl][S*8 ..+7]
  int rcK[4], rcV[4];
#pragma unroll
  for (int i = 0; i < 4; ++i) {
    int c = i * 128 + tid;
    int mK = c >> 7, h2 = (c >> 6) & 1, k2 = (c >> 5) & 1, r = c & 31;
    rcK[i] = (k2 * 32 + r) * DKq + (2 * mK + h2) * 8;
    int Sv = c >> 6, db = (c >> 5) & 1, dl = c & 31;
    rcV[i] = (db * 32 + dl) * SS + Sv * 8;
  }

  // Read bases (tile-invariant; m/kbk/S/dblk/buf are compile-time immediates):
  //  K(buf,kbk,m): Kb + bo + m*2048 + kbk*512     (Kb has +hi*1024 +l31*16)
  //  V(buf,S,dblk): Vb + bo + S*1024 + dblk*512   (Vb has +8192 +l31*16 +hi*8)
  const char* Kb = (const char*)&KV[0][0] + hi * 1024 + l31 * 16;
  const char* Vb = (const char*)&KV[0][0] + 8192 + l31 * 16 + hi * 8;

  const f32x16 z16 = {0,0,0,0,0,0,0,0,0,0,0,0,0,0,0,0};
  f32x16 oacc[2];
  oacc[0] = z16; oacc[1] = z16;
  float dsum = 0.f;

  const int toff = bid & 31;   // tile stagger: break inter-block phase-lock
  // prologue: stage physical tile toff into buf 0
  {
    const unsigned short* kS = kbase + (toff << 12);
    const unsigned short* vS = vbase + (toff << 6);
#pragma unroll
    for (int i = 0; i < 4; ++i) {
      gload_lds16(kS + rcK[i], &KV[0][i * 1024 + tid * 8]);
      gload_lds16(vS + rcV[i], &KV[0][4096 + i * 1024 + tid * 8]);
    }
  }
  int tn = 1;

#define TILE_BODY(BUF, PREFETCH)                                              \
  {                                                                           \
    asm volatile("s_waitcnt vmcnt(0)" ::: "memory");                          \
    __syncthreads();                                                          \
    __builtin_amdgcn_sched_barrier(0);                                        \
    if (PREFETCH) {                                                           \
      int ktN = (tn + toff) & 31;                                             \
      const unsigned short* kS = kbase + (ktN << 12);                         \
      const unsigned short* vS = vbase + (ktN << 6);                          \
      _Pragma("unroll")                                                       \
      for (int i = 0; i < 4; ++i) {                                           \
        gload_lds16(kS + rcK[i], &KV[(BUF) ^ 1][i * 1024 + tid * 8]);         \
        gload_lds16(vS + rcV[i], &KV[(BUF) ^ 1][4096 + i * 1024 + tid * 8]);  \
      }                                                                       \
      ++tn;                                                                   \
    }                                                                         \
    const int bo = (BUF) * 16384;                                             \
    f32x16 S0 = z16, S1 = z16;                                                \
    _Pragma("unroll")                                                         \
    for (int m = 0; m < 4; ++m) {                                             \
      bf16x8 a0 = *(const bf16x8*)(Kb + bo + m * 2048);                       \
      bf16x8 a1 = *(const bf16x8*)(Kb + bo + m * 2048 + 512);                 \
      S0 = __builtin_amdgcn_mfma_f32_32x32x16_bf16(a0, Qf[m], S0, 0, 0, 0);   \
      S1 = __builtin_amdgcn_mfma_f32_32x32x16_bf16(a1, Qf[m], S1, 0, 0, 0);   \
    }                                                                         \
    _Pragma("unroll")                                                         \
    for (int e = 0; e < 16; ++e) {                                            \
      S0[e] = fexp2(S0[e]);                                                   \
      S1[e] = fexp2(S1[e]);                                                   \
    }                                                                         \
    {                                                                         \
      f32x16 ps = S0 + S1;                                                    \
      float t8[8], t4[4], t2[2];                                              \
      _Pragma("unroll")                                                       \
      for (int e = 0; e < 8; ++e) t8[e] = ps[e] + ps[e + 8];                  \
      _Pragma("unroll")                                                       \
      for (int e = 0; e < 4; ++e) t4[e] = t8[e] + t8[e + 4];                  \
      t2[0] = t4[0] + t4[2]; t2[1] = t4[1] + t4[3];                           \
      dsum += t2[0] + t2[1];                                                  \
    }                                                                         \
    _Pragma("unroll")                                                         \
    for (int kbk = 0; kbk < 2; ++kbk) {                                       \
      _Pragma("unroll")                                                       \
      for (int c2 = 0; c2 < 2; ++c2) {                                        \
        bf16x8 pf;                                                            \
        _Pragma("unroll")                                                     \
        for (int j = 0; j < 8; ++j)                                           \
          pf[j] = (__bf16)((kbk == 0) ? S0[8 * c2 + j] : S1[8 * c2 + j]);     \
        const int s0i = 4 * kbk + 2 * c2;                                     \
        _Pragma("unroll")                                                     \
        for (int dblk = 0; dblk < 2; ++dblk) {                                \
          bf16x4 lo  = *(const bf16x4*)(Vb + bo + s0i * 1024 + dblk * 512);          \
          bf16x4 hi4 = *(const bf16x4*)(Vb + bo + (s0i + 1) * 1024 + dblk * 512);    \
          bf16x8 vfr = __builtin_shufflevector(lo, hi4, 0, 1, 2, 3, 4, 5, 6, 7);     \
          oacc[dblk] = __builtin_amdgcn_mfma_f32_32x32x16_bf16(vfr, pf, oacc[dblk], 0, 0, 0); \
        }                                                                     \
      }                                                                       \
    }                                                                         \
  }

  for (int t2i = 0; t2i < 15; ++t2i) {  // tiles 0..29
    TILE_BODY(0, 1)
    TILE_BODY(1, 1)
  }
  TILE_BODY(0, 1)                       // tile 30, prefetch 31
  TILE_BODY(1, 0)                       // tile 31
#undef TILE_BODY

  // finalize: cross-half rowsum, normalize, store O^T fragments as float4s
  float tot = dsum + __shfl_xor(dsum, 32);
  float inv = 1.0f / (tot + 1e-8f);
  float* ob = out + ((size_t)b * SS + qt * 64 + w * 32 + l31) * DM + h * DKq;
#pragma unroll
  for (int dblk = 0; dblk < 2; ++dblk)
#pragma unroll
    for (int g = 0; g < 4; ++g) {
      f32x4 v4 = { oacc[dblk][4 * g] * inv, oacc[dblk][4 * g + 1] * inv,
                   oacc[dblk][4 * g + 2] * inv, oacc[dblk][4 * g + 3] * inv };
      *(f32x4*)(ob + dblk * 32 + 8 * g + 4 * hi) = v4;
    }
}

extern "C" void kernel_launch(void* const* d_in, const int* in_sizes, int n_in,
                              void* d_out, int out_size, void* d_ws, size_t ws_size,
                              hipStream_t stream) {
  const float* Q  = (const float*)d_in[0];
  const float* Wq = (const float*)d_in[1];
  const float* bq = (const float*)d_in[2];
  const float* Wk = (const float*)d_in[3];
  const float* bk = (const float*)d_in[4];
  const float* Wv = (const float*)d_in[5];
  const float* bv = (const float*)d_in[6];
  char* ws = (char*)d_ws;
  const size_t MB = 1024 * 1024;
  unsigned short* Xbf = (unsigned short*)(ws);              // 8 MB
  unsigned short* W3  = (unsigned short*)(ws + 8 * MB);     // 6 MB
  unsigned short* qb  = (unsigned short*)(ws + 14 * MB);    // 8 MB
  unsigned short* kb  = (unsigned short*)(ws + 22 * MB);    // 8 MB
  unsigned short* vt  = (unsigned short*)(ws + 30 * MB);    // 8 MB -> total 38 MB

  cast_all<<<3584, 256, 0, stream>>>(Q, Wq, Wk, Wv, Xbf, W3);
  proj_gemm<<<dim3(32, 24), 256, 0, stream>>>(Xbf, W3, bq, bk, bv, qb, kb, vt);
  attn6<<<1024, 128, 0, stream>>>(qb, kb, vt, (float*)d_out);
}

// Round 9
// 96.981 us; speedup vs baseline: 1.2182x; 1.2182x over previous
//
#include <hip/hip_runtime.h>
#include <hip/hip_bf16.h>
#include <stdint.h>

#define DM 1024
#define NH 16
#define DKq 64
#define SS 2048

// fold 1/sqrt(Dk)=1/8 and log2(e) into K so P = exp2(S) directly
#define SCALE_K 0.18033688011112042f

typedef __bf16 bf16x8 __attribute__((ext_vector_type(8)));
typedef __bf16 bf16x4 __attribute__((ext_vector_type(4)));
typedef float f32x4 __attribute__((ext_vector_type(4)));
typedef float f32x16 __attribute__((ext_vector_type(16)));
typedef unsigned short u16x8 __attribute__((ext_vector_type(8)));

static __device__ __forceinline__ unsigned short f2bf(float f) {
  union { float f; unsigned u; } v; v.f = f;
  unsigned r = v.u + 0x7FFFu + ((v.u >> 16) & 1u);
  return (unsigned short)(r >> 16);
}

static __device__ __forceinline__ float fexp2(float x) {
  float r; asm("v_exp_f32 %0, %1" : "=v"(r) : "v"(x)); return r;
}

static __device__ __forceinline__ void gload_lds16(const void* g, void* l) {
  __builtin_amdgcn_global_load_lds((const __attribute__((address_space(1))) void*)g,
                                   (__attribute__((address_space(3))) void*)l, 16, 0, 0);
}

// ---- fused casts: X fp32->bf16, W{q,k,v} fp32->bf16 (Wk scaled) ----
__global__ void cast_all(const float* __restrict__ Q, const float* __restrict__ wq,
                         const float* __restrict__ wk, const float* __restrict__ wv,
                         unsigned short* __restrict__ Xb, unsigned short* __restrict__ W3) {
  int i = blockIdx.x * blockDim.x + threadIdx.x;  // 0 .. 917503
  const int nX8 = 4096 * 1024 / 8;                // 524288
  if (i < nX8) {
    const float4* s = reinterpret_cast<const float4*>(Q) + (size_t)i * 2;
    float4 a = s[0], b = s[1];
    u16x8 o;
    o[0]=f2bf(a.x); o[1]=f2bf(a.y); o[2]=f2bf(a.z); o[3]=f2bf(a.w);
    o[4]=f2bf(b.x); o[5]=f2bf(b.y); o[6]=f2bf(b.z); o[7]=f2bf(b.w);
    *reinterpret_cast<u16x8*>(Xb + (size_t)i * 8) = o;
  } else {
    int j = i - nX8;                 // 0 .. 393215
    int which = j >> 17;             // 131072 chunks per matrix
    int local = j & 131071;
    float sc = (which == 1) ? SCALE_K : 1.0f;
    const float* s = (which == 0 ? wq : (which == 1 ? wk : wv)) + (size_t)local * 8;
    float4 a = *(const float4*)s, b = *(const float4*)(s + 4);
    u16x8 o;
    o[0]=f2bf(a.x*sc); o[1]=f2bf(a.y*sc); o[2]=f2bf(a.z*sc); o[3]=f2bf(a.w*sc);
    o[4]=f2bf(b.x*sc); o[5]=f2bf(b.y*sc); o[6]=f2bf(b.z*sc); o[7]=f2bf(b.w*sc);
    *reinterpret_cast<u16x8*>(W3 + (size_t)j * 8) = o;
  }
}

// ---- fused QKV projection: [4096,1024] @ [3072,1024]^T + bias -> q/k (bhsd) , v (bhds) ----
__launch_bounds__(256)
__global__ void proj_gemm(const unsigned short* __restrict__ X, const unsigned short* __restrict__ W3,
                          const float* __restrict__ bq, const float* __restrict__ bk,
                          const float* __restrict__ bv,
                          unsigned short* __restrict__ qb, unsigned short* __restrict__ kbuf,
                          unsigned short* __restrict__ vt) {
  __shared__ __align__(16) unsigned short Ab[128 * 32];
  __shared__ __align__(16) unsigned short Bb[128 * 32];
  const int m0 = blockIdx.x * 128, n0 = blockIdx.y * 128;
  const int tid = threadIdx.x;
  const int w = tid >> 6, lane = tid & 63;
  const int i16 = lane & 15, kg = lane >> 4;
  const int wr = w >> 1, wc = w & 1;

  const int arow = tid >> 2, acol = (tid & 3) * 8;
  const unsigned short* Xp = X + (size_t)(m0 + arow) * DM + acol;
  const unsigned short* Wp = W3 + (size_t)(n0 + arow) * DM + acol;
  char* AbC = (char*)Ab;
  char* BbC = (char*)Bb;

  const f32x4 fz = {0.f, 0.f, 0.f, 0.f};
  f32x4 acc[4][4];
#pragma unroll
  for (int m = 0; m < 4; ++m)
#pragma unroll
    for (int n = 0; n < 4; ++n) acc[m][n] = fz;

  for (int k0 = 0; k0 < DM; k0 += 32) {
    gload_lds16(Xp + k0,            AbC + w * 1024);
    gload_lds16(Xp + 64 * DM + k0,  AbC + 4096 + w * 1024);
    gload_lds16(Wp + k0,            BbC + w * 1024);
    gload_lds16(Wp + 64 * DM + k0,  BbC + 4096 + w * 1024);
    __syncthreads();
    bf16x8 af[4], bfr[4];
#pragma unroll
    for (int m = 0; m < 4; ++m)
      af[m] = *(const bf16x8*)(AbC + ((wr * 64 + m * 16 + i16) * 32 + kg * 8) * 2);
#pragma unroll
    for (int n = 0; n < 4; ++n)
      bfr[n] = *(const bf16x8*)(BbC + ((wc * 64 + n * 16 + i16) * 32 + kg * 8) * 2);
#pragma unroll
    for (int m = 0; m < 4; ++m)
#pragma unroll
      for (int n = 0; n < 4; ++n)
        acc[m][n] = __builtin_amdgcn_mfma_f32_16x16x32_bf16(af[m], bfr[n], acc[m][n], 0, 0, 0);
    __syncthreads();
  }

#pragma unroll
  for (int n = 0; n < 4; ++n) {
    int ncol = n0 + wc * 64 + n * 16 + i16;
    int which = ncol >> 10, nn = ncol & 1023;
    const float* bias = (which == 0) ? bq : (which == 1) ? bk : bv;
    float bsv = bias[nn];
    if (which == 1) bsv *= SCALE_K;
    int h = nn >> 6, d = nn & 63;
#pragma unroll
    for (int m = 0; m < 4; ++m) {
      int rbase = m0 + wr * 64 + m * 16 + kg * 4;
#pragma unroll
      for (int e = 0; e < 4; ++e) {
        int r = rbase + e;
        int bI = r >> 11, s = r & 2047;
        if (which == 2) {
          vt[(((size_t)bI * NH + h) * DKq + d) * SS + s] = f2bf(acc[m][n][e] + bsv);
        } else {
          unsigned short* dst = (which == 0) ? qb : kbuf;
          dst[(((size_t)bI * NH + h) * SS + s) * DKq + d] = f2bf(acc[m][n][e] + bsv);
        }
      }
    }
  }
}

// ---- attention v8: attn5 state (proven layout/sync) + 2-stage software
// pipeline: epoch t = {barrier; prefetch t+1; QK(t) interleaved with exp(t-1);
// PV(t-1)}. K double-buffered, V triple-buffered (40 KB LDS, 4 blocks/CU). ----
__launch_bounds__(128)
__global__ void attn8(const unsigned short* __restrict__ qb, const unsigned short* __restrict__ kbuf,
                      const unsigned short* __restrict__ vt, float* __restrict__ out) {
  __shared__ __align__(16) unsigned short Kst[2][4096];  // 16 KB
  __shared__ __align__(16) unsigned short Vst[3][4096];  // 24 KB
  const int bid = blockIdx.x;
  const int work = (bid & 7) * 128 + (bid >> 3);  // XCD-grouped: 4 (b,h) per XCD
  const int qt = work & 31, h = (work >> 5) & 15, b = work >> 9;
  const int tid = threadIdx.x, w = tid >> 6, lane = tid & 63;
  const int l31 = lane & 31, hi = lane >> 5;

  const size_t bh = (size_t)b * NH + h;
  const unsigned short* qsrc = qb + (bh * SS + qt * 64 + w * 32) * DKq;
  const unsigned short* kbase = kbuf + bh * SS * DKq;
  const unsigned short* vbase = vt + bh * DKq * SS;

  // Q frags: B-operand of mfma(K,Q): lane holds Q[q = l31][kd = m*16 + hi*8 + j]
  bf16x8 Qf[4];
#pragma unroll
  for (int m = 0; m < 4; ++m)
    Qf[m] = *(const bf16x8*)(qsrc + (size_t)l31 * DKq + m * 16 + hi * 8);

  // staging: 512 16B-chunks each for K and V over 128 threads (4+4/thread);
  // source-slot swizzle ^(row&7); dest is linear (both-sides rule)
  const unsigned short* kp[4];
  const unsigned short* vp[4];
  int ldo[4];
#pragma unroll
  for (int i = 0; i < 4; ++i) {
    int c = i * 128 + tid;
    int row = c >> 3, sl = (c & 7) ^ (row & 7);
    kp[i] = kbase + (size_t)row * DKq + sl * 8;
    vp[i] = vbase + (size_t)row * SS + sl * 8;
    ldo[i] = c * 8;
  }

  // hoisted LDS read addressing (tile-invariant):
  //  K(buf,kbk,m): Kb + koff[m] + buf*8192 + kbk*4096
  //  V(vfo,dblk,s): Vb + vfo + voff[s] + dblk*4096   (+hi*8 folded in Vb)
  const int swz = l31 & 7;
  const char* Kb = (const char*)&Kst[0][0] + l31 * 128;
  const char* Vb = (const char*)&Vst[0][0] + l31 * 128 + hi * 8;
  int koff[4];
#pragma unroll
  for (int m = 0; m < 4; ++m) koff[m] = ((2 * m + hi) ^ swz) * 16;
  int voff[8];
#pragma unroll
  for (int s = 0; s < 8; ++s) voff[s] = (s ^ swz) * 16;

  const f32x16 z16 = {0,0,0,0,0,0,0,0,0,0,0,0,0,0,0,0};
  f32x16 oacc[2];
  oacc[0] = z16; oacc[1] = z16;
  float dsum = 0.f;
  f32x16 Sa0 = z16, Sa1 = z16, Sb0 = z16, Sb1 = z16;

  unsigned short* vstg = &Vst[1][0];   // next V stage dest (tile 1)
  int vfo = 0;                          // V read base for FINISH (tile 0)

  // prologue: stage tile 0 (K->Kst[0], V->Vst[0])
#pragma unroll
  for (int i = 0; i < 4; ++i) {
    gload_lds16(kp[i], &Kst[0][ldo[i]]);
    gload_lds16(vp[i], &Vst[0][ldo[i]]);
    kp[i] += 4096; vp[i] += 64;
  }

#define BARRIER_TOP()                                                         \
    asm volatile("s_waitcnt vmcnt(0)" ::: "memory");                          \
    __syncthreads();                                                          \
    __builtin_amdgcn_sched_barrier(0);

#define PREFETCH(KDST)                                                        \
    {                                                                         \
      _Pragma("unroll")                                                       \
      for (int i = 0; i < 4; ++i) {                                           \
        gload_lds16(kp[i], &Kst[KDST][ldo[i]]);                               \
        gload_lds16(vp[i], vstg + ldo[i]);                                    \
        kp[i] += 4096; vp[i] += 64;                                           \
      }                                                                       \
      vstg = (vstg == &Vst[2][0]) ? &Vst[0][0] : vstg + 4096;                 \
    }

// QK of current tile (reads Kst at byte base BOK into SC0/SC1) hand-interleaved
// with exp2 of the previous tile's scores (SP0/SP1), 8 exps per m-step.
#define QK_EXP(BOK, SC0, SC1, SP0, SP1, DO_FIN)                               \
    SC0 = z16; SC1 = z16;                                                     \
    {                                                                         \
      bf16x8 a0, a1;                                                          \
      a0 = *(const bf16x8*)(Kb + koff[0] + (BOK));                            \
      a1 = *(const bf16x8*)(Kb + koff[0] + (BOK) + 4096);                     \
      SC0 = __builtin_amdgcn_mfma_f32_32x32x16_bf16(a0, Qf[0], SC0, 0, 0, 0); \
      SC1 = __builtin_amdgcn_mfma_f32_32x32x16_bf16(a1, Qf[0], SC1, 0, 0, 0); \
      if (DO_FIN) { _Pragma("unroll") for (int e = 0; e < 8; ++e) SP0[e] = fexp2(SP0[e]); } \
      a0 = *(const bf16x8*)(Kb + koff[1] + (BOK));                            \
      a1 = *(const bf16x8*)(Kb + koff[1] + (BOK) + 4096);                     \
      SC0 = __builtin_amdgcn_mfma_f32_32x32x16_bf16(a0, Qf[1], SC0, 0, 0, 0); \
      SC1 = __builtin_amdgcn_mfma_f32_32x32x16_bf16(a1, Qf[1], SC1, 0, 0, 0); \
      if (DO_FIN) { _Pragma("unroll") for (int e = 8; e < 16; ++e) SP0[e] = fexp2(SP0[e]); } \
      a0 = *(const bf16x8*)(Kb + koff[2] + (BOK));                            \
      a1 = *(const bf16x8*)(Kb + koff[2] + (BOK) + 4096);                     \
      SC0 = __builtin_amdgcn_mfma_f32_32x32x16_bf16(a0, Qf[2], SC0, 0, 0, 0); \
      SC1 = __builtin_amdgcn_mfma_f32_32x32x16_bf16(a1, Qf[2], SC1, 0, 0, 0); \
      if (DO_FIN) { _Pragma("unroll") for (int e = 0; e < 8; ++e) SP1[e] = fexp2(SP1[e]); } \
      a0 = *(const bf16x8*)(Kb + koff[3] + (BOK));                            \
      a1 = *(const bf16x8*)(Kb + koff[3] + (BOK) + 4096);                     \
      SC0 = __builtin_amdgcn_mfma_f32_32x32x16_bf16(a0, Qf[3], SC0, 0, 0, 0); \
      SC1 = __builtin_amdgcn_mfma_f32_32x32x16_bf16(a1, Qf[3], SC1, 0, 0, 0); \
      if (DO_FIN) { _Pragma("unroll") for (int e = 8; e < 16; ++e) SP1[e] = fexp2(SP1[e]); } \
    }

// dsum + pack + PV of the previous tile (SP already exp'd); reads V at Vb+vfo.
#define FINISH_PV(SP0, SP1)                                                   \
    {                                                                         \
      f32x16 ps = SP0 + SP1;                                                  \
      float t8[8], t4[4];                                                     \
      _Pragma("unroll")                                                       \
      for (int e = 0; e < 8; ++e) t8[e] = ps[e] + ps[e + 8];                  \
      _Pragma("unroll")                                                       \
      for (int e = 0; e < 4; ++e) t4[e] = t8[e] + t8[e + 4];                  \
      dsum += (t4[0] + t4[2]) + (t4[1] + t4[3]);                              \
      const char* Vr = Vb + vfo;                                              \
      _Pragma("unroll")                                                       \
      for (int kbk = 0; kbk < 2; ++kbk) {                                     \
        _Pragma("unroll")                                                     \
        for (int c2 = 0; c2 < 2; ++c2) {                                      \
          bf16x8 pf;                                                          \
          _Pragma("unroll")                                                   \
          for (int j = 0; j < 8; ++j)                                         \
            pf[j] = (__bf16)((kbk == 0) ? SP0[8 * c2 + j] : SP1[8 * c2 + j]); \
          _Pragma("unroll")                                                   \
          for (int dblk = 0; dblk < 2; ++dblk) {                              \
            bf16x4 lo  = *(const bf16x4*)(Vr + voff[4 * kbk + 2 * c2] + dblk * 4096);      \
            bf16x4 hi4 = *(const bf16x4*)(Vr + voff[4 * kbk + 2 * c2 + 1] + dblk * 4096);  \
            bf16x8 vfr = __builtin_shufflevector(lo, hi4, 0, 1, 2, 3, 4, 5, 6, 7);         \
            oacc[dblk] = __builtin_amdgcn_mfma_f32_32x32x16_bf16(vfr, pf, oacc[dblk], 0, 0, 0); \
          }                                                                   \
        }                                                                     \
      }                                                                       \
      vfo = (vfo == 16384) ? 0 : vfo + 8192;                                  \
    }

  // epoch 0: stage(0) landed; prefetch 1; QK(0)->Sa (no finish)
  BARRIER_TOP()
  PREFETCH(1)
  QK_EXP(0, Sa0, Sa1, Sb0, Sb1, 0)

  // epoch 1: prefetch 2; QK(1)->Sb ∥ exp(Sa); PV(0)
  BARRIER_TOP()
  PREFETCH(0)
  QK_EXP(8192, Sb0, Sb1, Sa0, Sa1, 1)
  FINISH_PV(Sa0, Sa1)

  for (int it = 0; it < 14; ++it) {   // epochs 2..29
    BARRIER_TOP()
    PREFETCH(1)
    QK_EXP(0, Sa0, Sa1, Sb0, Sb1, 1)
    FINISH_PV(Sb0, Sb1)
    BARRIER_TOP()
    PREFETCH(0)
    QK_EXP(8192, Sb0, Sb1, Sa0, Sa1, 1)
    FINISH_PV(Sa0, Sa1)
  }

  // epoch 30: prefetch 31; QK(30)->Sa ∥ exp(Sb); PV(29)
  BARRIER_TOP()
  PREFETCH(1)
  QK_EXP(0, Sa0, Sa1, Sb0, Sb1, 1)
  FINISH_PV(Sb0, Sb1)

  // epoch 31: no prefetch; QK(31)->Sb ∥ exp(Sa); PV(30)
  BARRIER_TOP()
  QK_EXP(8192, Sb0, Sb1, Sa0, Sa1, 1)
  FINISH_PV(Sa0, Sa1)

  // epilogue: exp + PV of tile 31
#pragma unroll
  for (int e = 0; e < 16; ++e) { Sb0[e] = fexp2(Sb0[e]); Sb1[e] = fexp2(Sb1[e]); }
  FINISH_PV(Sb0, Sb1)

#undef BARRIER_TOP
#undef PREFETCH
#undef QK_EXP
#undef FINISH_PV

  // finalize: cross-half rowsum, normalize, store O^T fragments as float4s
  float tot = dsum + __shfl_xor(dsum, 32);
  float inv = 1.0f / (tot + 1e-8f);
  float* ob = out + ((size_t)b * SS + qt * 64 + w * 32 + l31) * DM + h * DKq;
#pragma unroll
  for (int dblk = 0; dblk < 2; ++dblk)
#pragma unroll
    for (int g = 0; g < 4; ++g) {
      f32x4 v4 = { oacc[dblk][4 * g] * inv, oacc[dblk][4 * g + 1] * inv,
                   oacc[dblk][4 * g + 2] * inv, oacc[dblk][4 * g + 3] * inv };
      *(f32x4*)(ob + dblk * 32 + 8 * g + 4 * hi) = v4;
    }
}

extern "C" void kernel_launch(void* const* d_in, const int* in_sizes, int n_in,
                              void* d_out, int out_size, void* d_ws, size_t ws_size,
                              hipStream_t stream) {
  const float* Q  = (const float*)d_in[0];
  const float* Wq = (const float*)d_in[1];
  const float* bq = (const float*)d_in[2];
  const float* Wk = (const float*)d_in[3];
  const float* bk = (const float*)d_in[4];
  const float* Wv = (const float*)d_in[5];
  const float* bv = (const float*)d_in[6];
  char* ws = (char*)d_ws;
  const size_t MB = 1024 * 1024;
  unsigned short* Xbf = (unsigned short*)(ws);              // 8 MB
  unsigned short* W3  = (unsigned short*)(ws + 8 * MB);     // 6 MB
  unsigned short* qb  = (unsigned short*)(ws + 14 * MB);    // 8 MB
  unsigned short* kb  = (unsigned short*)(ws + 22 * MB);    // 8 MB
  unsigned short* vt  = (unsigned short*)(ws + 30 * MB);    // 8 MB -> total 38 MB

  cast_all<<<3584, 256, 0, stream>>>(Q, Wq, Wk, Wv, Xbf, W3);
  proj_gemm<<<dim3(32, 24), 256, 0, stream>>>(Xbf, W3, bq, bk, bv, qb, kb, vt);
  attn8<<<1024, 128, 0, stream>>>(qb, kb, vt, (float*)d_out);
}